// Round 7
// baseline (187.586 us; speedup 1.0000x reference)
//
#include <hip/hip_runtime.h>
#include <hip/hip_bf16.h>

#define NB   8192   // batch
#define NS   10     // neighbor seq len
#define NT   3      // node types
#define NN   65536  // table size
#define ND   128    // embed dim
#define NL   2      // layers
#define ROWS 32     // batch rows per block

typedef __attribute__((ext_vector_type(8))) short bf16x8;
typedef __attribute__((ext_vector_type(4))) float f32x4;

__device__ __forceinline__ unsigned int pk2(float lo, float hi) {
    unsigned int r;
    asm("v_cvt_pk_bf16_f32 %0, %1, %2" : "=v"(r) : "v"(lo), "v"(hi));
    return r;
}
__device__ __forceinline__ float fast_tanh(float x) {
    float e = __expf(2.0f * x);
    return 1.0f - __fdividef(2.0f, e + 1.0f);
}
// Barrier with LDS-only drain: global (vmcnt) loads stay in flight across it.
__device__ __forceinline__ void bar_lgkm() {
    asm volatile("s_waitcnt lgkmcnt(0)\n\ts_barrier" ::: "memory");
}

// ---------------------------------------------------------------------------
// RNN kernel: grid = NL*NT*256 blocks, 256 threads (4 waves).
// Block owns (l, t, 32 batch rows). Wave w owns e-range [w*32, w*32+32).
// W2 = [Wih;Whh] in registers as MFMA A-fragments. X_s and H staged in LDS
// (bf16, XOR-swizzled 16B chunks). Next-step gather prefetched into registers;
// lgkm-only barriers keep those loads in flight across the step (T4/T14).
// ---------------------------------------------------------------------------
__global__ __launch_bounds__(256, 4)
void rnn_kernel(const float* __restrict__ emb, const float* __restrict__ Wih,
                const float* __restrict__ Whh, const float* __restrict__ bih,
                const float* __restrict__ bhh, const int* __restrict__ nidx,
                float* __restrict__ agg)
{
    __shared__ __align__(16) unsigned short Xs[ROWS * 128];   // 8 KB
    __shared__ __align__(16) unsigned short Hs[ROWS * 128];   // 8 KB
    char* xb = (char*)Xs;
    char* hb = (char*)Hs;

    const int bid = blockIdx.x;
    const int l   = bid / (NT * (NB / ROWS));
    const int t   = (bid / (NB / ROWS)) % NT;
    const int b0  = (bid % (NB / ROWS)) * ROWS;

    const int tid  = threadIdx.x;
    const int w    = tid >> 6;
    const int lane = tid & 63;
    const int l16  = lane & 15;
    const int lg   = lane >> 4;
    const int e0   = w * 32;
    const int rx   = l16 & 7;        // read-swizzle key (row%8 == l16%8)

    const float* Wih_lt = Wih + (size_t)(l * NT + t) * ND * ND;
    const float* Whh_lt = Whh + (size_t)(l * NT + t) * ND * ND;
    const float* bih_lt = bih + (size_t)(l * NT + t) * ND;
    const float* bhh_lt = bhh + (size_t)(l * NT + t) * ND;

    // staging geometry: 8 threads per row, 16 d each
    const int srow = tid >> 3;       // 0..31
    const int sq   = tid & 7;        // d-sixteenth (16 floats)
    const int ssw  = srow & 7;       // write-swizzle key

    // ---- preload all neighbor indices for this row ----
    const int* ip = nidx + ((size_t)t * NB + b0 + srow) * NS;
    int idxs[NS];
    #pragma unroll
    for (int s = 0; s < NS; ++s) idxs[s] = ip[s];

    // ---- prefetch s=0 gather (lands while W-fragments are built) ----
    float4 P[4];
    {
        const float* src = emb + ((size_t)t * NN + idxs[0]) * ND + sq * 16;
        #pragma unroll
        for (int c = 0; c < 4; ++c) P[c] = *(const float4*)(src + c * 4);
    }

    // ---- A-fragments: rows e = e0 + mt*16 + l16, k-chunk kc (kc<4: Wih, else Whh) ----
    bf16x8 Af[2][8];
    #pragma unroll
    for (int mt = 0; mt < 2; ++mt) {
        #pragma unroll
        for (int kc = 0; kc < 8; ++kc) {
            const float* Wsrc = (kc < 4) ? Wih_lt : Whh_lt;
            const float* srcp = Wsrc + (size_t)(e0 + mt * 16 + l16) * ND + (kc & 3) * 32 + lg * 8;
            float4 p0 = *(const float4*)(srcp);
            float4 p1 = *(const float4*)(srcp + 4);
            int4 a;
            a.x = (int)pk2(p0.x, p0.y);
            a.y = (int)pk2(p0.z, p0.w);
            a.z = (int)pk2(p1.x, p1.y);
            a.w = (int)pk2(p1.z, p1.w);
            Af[mt][kc] = *(bf16x8*)&a;
        }
    }

    float bias[2][4];
    #pragma unroll
    for (int mt = 0; mt < 2; ++mt)
        #pragma unroll
        for (int i = 0; i < 4; ++i) {
            int e = e0 + mt * 16 + lg * 4 + i;
            bias[mt][i] = bih_lt[e] + bhh_lt[e];
        }

    f32x4 zero4; zero4[0] = 0.f; zero4[1] = 0.f; zero4[2] = 0.f; zero4[3] = 0.f;
    f32x4 Ag[2][2];
    #pragma unroll
    for (int nt = 0; nt < 2; ++nt) { Ag[nt][0] = zero4; Ag[nt][1] = zero4; }

    for (int s = 0; s < NS; ++s) {
        // ---- pack prefetched X_s -> swizzled LDS store (2x ds_write_b128) ----
        #pragma unroll
        for (int j = 0; j < 2; ++j) {
            int4 pk;
            pk.x = (int)pk2(P[2 * j].x,     P[2 * j].y);
            pk.y = (int)pk2(P[2 * j].z,     P[2 * j].w);
            pk.z = (int)pk2(P[2 * j + 1].x, P[2 * j + 1].y);
            pk.w = (int)pk2(P[2 * j + 1].z, P[2 * j + 1].w);
            int chunk = (2 * sq + j) ^ ssw;
            *(int4*)(xb + srow * 256 + (chunk << 4)) = pk;
        }
        // ---- issue next-step gather; stays in flight across both barriers ----
        if (s + 1 < NS) {
            const float* src = emb + ((size_t)t * NN + idxs[s + 1]) * ND + sq * 16;
            #pragma unroll
            for (int c = 0; c < 4; ++c) P[c] = *(const float4*)(src + c * 4);
        }
        bar_lgkm();   // Xs visible; prior-step H writes visible; vmcnt NOT drained

        // ---- acc[nt][mt] = W2-rows x Z-rows (K = 256: X then H) ----
        f32x4 acc[2][2];
        #pragma unroll
        for (int nt = 0; nt < 2; ++nt) { acc[nt][0] = zero4; acc[nt][1] = zero4; }

        #pragma unroll
        for (int nt = 0; nt < 2; ++nt) {
            const int r = nt * 16 + l16;
            #pragma unroll
            for (int kc = 0; kc < 8; ++kc) {
                if (kc < 4 || s > 0) {      // h0 == 0: skip H-matmul at s==0
                    const char* buf = (kc < 4) ? xb : hb;
                    int chunk = ((kc & 3) * 4 + lg) ^ rx;
                    bf16x8 bf = *(const bf16x8*)(buf + r * 256 + (chunk << 4));
                    acc[nt][0] = __builtin_amdgcn_mfma_f32_16x16x32_bf16(Af[0][kc], bf, acc[nt][0], 0, 0, 0);
                    acc[nt][1] = __builtin_amdgcn_mfma_f32_16x16x32_bf16(Af[1][kc], bf, acc[nt][1], 0, 0, 0);
                }
            }
        }
        bar_lgkm();   // all X/H reads complete before Xs/Hs overwritten

        // ---- tanh + agg accumulate + packed H writeback ----
        #pragma unroll
        for (int nt = 0; nt < 2; ++nt) {
            const int r = nt * 16 + l16;
            const int rr = r & 7;
            #pragma unroll
            for (int mt = 0; mt < 2; ++mt) {
                f32x4 h;
                #pragma unroll
                for (int i = 0; i < 4; ++i)
                    h[i] = fast_tanh(acc[nt][mt][i] + bias[mt][i]);
                Ag[nt][mt] += h;
                int2 pk;
                pk.x = (int)pk2(h[0], h[1]);
                pk.y = (int)pk2(h[2], h[3]);
                int estart = e0 + mt * 16 + lg * 4;   // 4 consecutive e, fixed row r
                int chunk  = (estart >> 3) ^ rr;
                *(int2*)(hb + r * 256 + (chunk << 4) + (estart & 7) * 2) = pk;
            }
        }
        // next iteration's first bar_lgkm orders these H writes for readers
    }

    // agg[l][t][b][e]: lane writes float4 of 4 consecutive e at its row b
    float* aggp = agg + ((size_t)(l * NT + t) * NB + b0) * ND;
    #pragma unroll
    for (int nt = 0; nt < 2; ++nt) {
        int b = nt * 16 + l16;
        #pragma unroll
        for (int mt = 0; mt < 2; ++mt) {
            f32x4 v = Ag[nt][mt] * 0.1f;
            *(f32x4*)(aggp + (size_t)b * ND + e0 + mt * 16 + lg * 4) = v;
        }
    }
}

// ---------------------------------------------------------------------------
// Attention: one wave per batch row (lane covers d and d+64). 5 dots via
// shuffle reduce, softmax(4), weighted sum, leaky_relu. 2048 blocks x 256.
// ---------------------------------------------------------------------------
__global__ __launch_bounds__(256)
void att_kernel(const float* __restrict__ emb, const int* __restrict__ ids,
                const float* __restrict__ w_att, const float* __restrict__ agg,
                float* __restrict__ cur, const int l)
{
    const int wid  = threadIdx.x >> 6;
    const int lane = threadIdx.x & 63;
    const int b    = blockIdx.x * 4 + wid;

    const float* waH  = w_att + l * 2 * ND;
    const float* waT  = waH + ND;
    const float* crow = (l == 0) ? (emb + (size_t)ids[b] * ND) : (cur + (size_t)b * ND);
    const float* ab   = agg + ((size_t)(l * NT) * NB + b) * ND;   // + tt*NB*ND

    const float c1 = crow[lane], c2 = crow[lane + 64];
    const float h1 = waH[lane],  h2 = waH[lane + 64];
    const float t1 = waT[lane],  t2 = waT[lane + 64];
    float g1[3], g2[3];
    #pragma unroll
    for (int tt = 0; tt < 3; ++tt) {
        g1[tt] = ab[(size_t)tt * NB * ND + lane];
        g2[tt] = ab[(size_t)tt * NB * ND + lane + 64];
    }

    float dH = c1 * h1 + c2 * h2;
    float dc = c1 * t1 + c2 * t2;
    float d0 = g1[0] * t1 + g2[0] * t2;
    float d1 = g1[1] * t1 + g2[1] * t2;
    float d2 = g1[2] * t1 + g2[2] * t2;
    #pragma unroll
    for (int off = 32; off > 0; off >>= 1) {
        dH += __shfl_xor(dH, off);
        dc += __shfl_xor(dc, off);
        d0 += __shfl_xor(d0, off);
        d1 += __shfl_xor(d1, off);
        d2 += __shfl_xor(d2, off);
    }

    float s0 = dH + dc, s1 = dH + d0, s2 = dH + d1, s3 = dH + d2;
    float m  = fmaxf(fmaxf(s0, s1), fmaxf(s2, s3));
    float q0 = __expf(s0 - m), q1 = __expf(s1 - m), q2 = __expf(s2 - m), q3 = __expf(s3 - m);
    float inv = __fdividef(1.0f, q0 + q1 + q2 + q3);
    float w0 = q0 * inv, w1 = q1 * inv, w2 = q2 * inv, w3 = q3 * inv;

    float o1 = w0 * c1 + w1 * g1[0] + w2 * g1[1] + w3 * g1[2];
    float o2 = w0 * c2 + w1 * g2[0] + w2 * g2[1] + w3 * g2[2];
    o1 = (o1 > 0.f) ? o1 : 0.01f * o1;
    o2 = (o2 > 0.f) ? o2 : 0.01f * o2;

    float* orow = cur + (size_t)b * ND;
    orow[lane]      = o1;
    orow[lane + 64] = o2;
}

extern "C" void kernel_launch(void* const* d_in, const int* in_sizes, int n_in,
                              void* d_out, int out_size, void* d_ws, size_t ws_size,
                              hipStream_t stream)
{
    const float* emb  = (const float*)d_in[0];
    const float* Wih  = (const float*)d_in[1];
    const float* Whh  = (const float*)d_in[2];
    const float* bih  = (const float*)d_in[3];
    const float* bhh  = (const float*)d_in[4];
    const float* watt = (const float*)d_in[5];
    const int*   ids  = (const int*)d_in[6];
    const int*   nidx = (const int*)d_in[7];

    float* cur = (float*)d_out;            // [B][D] fp32, final output
    float* agg = (float*)d_ws;             // [L][T][B][D] fp32 = 25 MB

    rnn_kernel<<<dim3(NL * NT * (NB / ROWS)), dim3(256), 0, stream>>>(emb, Wih, Whh, bih, bhh, nidx, agg);
    att_kernel<<<dim3(NB / 4), dim3(256), 0, stream>>>(emb, ids, watt, agg, cur, 0);
    att_kernel<<<dim3(NB / 4), dim3(256), 0, stream>>>(emb, ids, watt, agg, cur, 1);
}

// Round 8
// 88.912 us; speedup vs baseline: 2.1098x; 2.1098x over previous
//
#include <hip/hip_runtime.h>
#include <hip/hip_bf16.h>

#define NB   8192   // batch
#define NS   10     // neighbor seq len
#define NT   3      // node types
#define NN   65536  // table size
#define ND   128    // embed dim
#define NL   2      // layers
#define ROWS 32     // batch rows per block

typedef __attribute__((ext_vector_type(8))) short bf16x8;
typedef __attribute__((ext_vector_type(4))) float f32x4;

__device__ __forceinline__ unsigned int pk2(float lo, float hi) {
    unsigned int r;
    asm("v_cvt_pk_bf16_f32 %0, %1, %2" : "=v"(r) : "v"(lo), "v"(hi));
    return r;
}
__device__ __forceinline__ float fast_tanh(float x) {
    float e = __expf(2.0f * x);
    return 1.0f - __fdividef(2.0f, e + 1.0f);
}
// Barrier with LDS-only drain: global (vmcnt) loads stay in flight across it.
__device__ __forceinline__ void bar_lgkm() {
    asm volatile("s_waitcnt lgkmcnt(0)\n\ts_barrier" ::: "memory");
}

// ---------------------------------------------------------------------------
// RNN kernel: grid = NL*NT*256 blocks, 256 threads (4 waves).
// Block owns (l, t, 32 batch rows). Wave w owns e-range [w*32, w*32+32).
// W2 = [Wih;Whh] in registers as MFMA A-fragments. X_s and H double-buffered
// in LDS (bf16, XOR-swizzled 16B chunks) -> ONE lgkm-only barrier per step:
// one wave's tanh/H-write overlaps another's MFMA; the register-prefetched
// gather (T14) stays in flight across the barrier (vmcnt not drained).
// Hazards: buffer written after bar(s) is read only after bar(s+1); each wave
// drains lgkmcnt(0) at its barrier, so writes are visible and reads complete.
// ---------------------------------------------------------------------------
__global__ __launch_bounds__(256)
void rnn_kernel(const float* __restrict__ emb, const float* __restrict__ Wih,
                const float* __restrict__ Whh, const float* __restrict__ bih,
                const float* __restrict__ bhh, const int* __restrict__ nidx,
                float* __restrict__ agg)
{
    __shared__ __align__(16) unsigned short Xs[2][ROWS * 128];   // 2 x 8 KB
    __shared__ __align__(16) unsigned short Hs[2][ROWS * 128];   // 2 x 8 KB

    const int bid = blockIdx.x;
    const int l   = bid / (NT * (NB / ROWS));
    const int t   = (bid / (NB / ROWS)) % NT;
    const int b0  = (bid % (NB / ROWS)) * ROWS;

    const int tid  = threadIdx.x;
    const int w    = tid >> 6;
    const int lane = tid & 63;
    const int l16  = lane & 15;
    const int lg   = lane >> 4;
    const int e0   = w * 32;
    const int rx   = l16 & 7;        // read-swizzle key (row%8 == l16%8)

    const float* Wih_lt = Wih + (size_t)(l * NT + t) * ND * ND;
    const float* Whh_lt = Whh + (size_t)(l * NT + t) * ND * ND;
    const float* bih_lt = bih + (size_t)(l * NT + t) * ND;
    const float* bhh_lt = bhh + (size_t)(l * NT + t) * ND;

    // staging geometry: 8 threads per row, 16 d each
    const int srow = tid >> 3;       // 0..31
    const int sq   = tid & 7;        // d-sixteenth (16 floats)
    const int ssw  = srow & 7;       // write-swizzle key

    // ---- preload all neighbor indices for this row ----
    const int* ip = nidx + ((size_t)t * NB + b0 + srow) * NS;
    int idxs[NS];
    #pragma unroll
    for (int s = 0; s < NS; ++s) idxs[s] = ip[s];

    // ---- prefetch s=0 gather (lands while W-fragments are built) ----
    float4 P[4];
    {
        const float* src = emb + ((size_t)t * NN + idxs[0]) * ND + sq * 16;
        #pragma unroll
        for (int c = 0; c < 4; ++c) P[c] = *(const float4*)(src + c * 4);
    }

    // ---- A-fragments: rows e = e0 + mt*16 + l16, k-chunk kc (kc<4: Wih, else Whh) ----
    bf16x8 Af[2][8];
    #pragma unroll
    for (int mt = 0; mt < 2; ++mt) {
        #pragma unroll
        for (int kc = 0; kc < 8; ++kc) {
            const float* Wsrc = (kc < 4) ? Wih_lt : Whh_lt;
            const float* srcp = Wsrc + (size_t)(e0 + mt * 16 + l16) * ND + (kc & 3) * 32 + lg * 8;
            float4 p0 = *(const float4*)(srcp);
            float4 p1 = *(const float4*)(srcp + 4);
            int4 a;
            a.x = (int)pk2(p0.x, p0.y);
            a.y = (int)pk2(p0.z, p0.w);
            a.z = (int)pk2(p1.x, p1.y);
            a.w = (int)pk2(p1.z, p1.w);
            Af[mt][kc] = *(bf16x8*)&a;
        }
    }

    float bias[2][4];
    #pragma unroll
    for (int mt = 0; mt < 2; ++mt)
        #pragma unroll
        for (int i = 0; i < 4; ++i) {
            int e = e0 + mt * 16 + lg * 4 + i;
            bias[mt][i] = bih_lt[e] + bhh_lt[e];
        }

    f32x4 zero4; zero4[0] = 0.f; zero4[1] = 0.f; zero4[2] = 0.f; zero4[3] = 0.f;
    f32x4 Ag[2][2];
    #pragma unroll
    for (int nt = 0; nt < 2; ++nt) { Ag[nt][0] = zero4; Ag[nt][1] = zero4; }

    for (int s = 0; s < NS; ++s) {
        char* xcur = (char*)Xs[s & 1];
        char* hprv = (char*)Hs[(s + 1) & 1];   // == (s-1)&1
        char* hcur = (char*)Hs[s & 1];

        // ---- pack prefetched X_s -> swizzled LDS store (2x ds_write_b128) ----
        #pragma unroll
        for (int j = 0; j < 2; ++j) {
            int4 pk;
            pk.x = (int)pk2(P[2 * j].x,     P[2 * j].y);
            pk.y = (int)pk2(P[2 * j].z,     P[2 * j].w);
            pk.z = (int)pk2(P[2 * j + 1].x, P[2 * j + 1].y);
            pk.w = (int)pk2(P[2 * j + 1].z, P[2 * j + 1].w);
            int chunk = (2 * sq + j) ^ ssw;
            *(int4*)(xcur + srow * 256 + (chunk << 4)) = pk;
        }
        // ---- issue next-step gather; stays in flight across the barrier ----
        if (s + 1 < NS) {
            const float* src = emb + ((size_t)t * NN + idxs[s + 1]) * ND + sq * 16;
            #pragma unroll
            for (int c = 0; c < 4; ++c) P[c] = *(const float4*)(src + c * 4);
        }
        bar_lgkm();   // X_s and H_{s-1} visible; prior reads complete; vmcnt in flight

        // ---- acc[nt][mt] = W2-rows x Z-rows (K = 256: X then H) ----
        f32x4 acc[2][2];
        #pragma unroll
        for (int nt = 0; nt < 2; ++nt) { acc[nt][0] = zero4; acc[nt][1] = zero4; }

        #pragma unroll
        for (int nt = 0; nt < 2; ++nt) {
            const int r = nt * 16 + l16;
            #pragma unroll
            for (int kc = 0; kc < 8; ++kc) {
                if (kc < 4 || s > 0) {      // h0 == 0: skip H-matmul at s==0
                    const char* buf = (kc < 4) ? xcur : hprv;
                    int chunk = ((kc & 3) * 4 + lg) ^ rx;
                    bf16x8 bf = *(const bf16x8*)(buf + r * 256 + (chunk << 4));
                    acc[nt][0] = __builtin_amdgcn_mfma_f32_16x16x32_bf16(Af[0][kc], bf, acc[nt][0], 0, 0, 0);
                    acc[nt][1] = __builtin_amdgcn_mfma_f32_16x16x32_bf16(Af[1][kc], bf, acc[nt][1], 0, 0, 0);
                }
            }
        }

        // ---- tanh + agg accumulate + packed H writeback (no barrier needed:
        //      H_s goes to the other buffer; readers sync at next bar_lgkm) ----
        #pragma unroll
        for (int nt = 0; nt < 2; ++nt) {
            const int r = nt * 16 + l16;
            const int rr = r & 7;
            #pragma unroll
            for (int mt = 0; mt < 2; ++mt) {
                f32x4 h;
                #pragma unroll
                for (int i = 0; i < 4; ++i)
                    h[i] = fast_tanh(acc[nt][mt][i] + bias[mt][i]);
                Ag[nt][mt] += h;
                int2 pk;
                pk.x = (int)pk2(h[0], h[1]);
                pk.y = (int)pk2(h[2], h[3]);
                int estart = e0 + mt * 16 + lg * 4;   // 4 consecutive e, fixed row r
                int chunk  = (estart >> 3) ^ rr;
                *(int2*)(hcur + r * 256 + (chunk << 4) + (estart & 7) * 2) = pk;
            }
        }
    }

    // agg[l][t][b][e]: lane writes float4 of 4 consecutive e at its row b
    float* aggp = agg + ((size_t)(l * NT + t) * NB + b0) * ND;
    #pragma unroll
    for (int nt = 0; nt < 2; ++nt) {
        int b = nt * 16 + l16;
        #pragma unroll
        for (int mt = 0; mt < 2; ++mt) {
            f32x4 v = Ag[nt][mt] * 0.1f;
            *(f32x4*)(aggp + (size_t)b * ND + e0 + mt * 16 + lg * 4) = v;
        }
    }
}

// ---------------------------------------------------------------------------
// Attention: one wave per batch row (lane covers d and d+64). 5 dots via
// shuffle reduce, softmax(4), weighted sum, leaky_relu. 2048 blocks x 256.
// ---------------------------------------------------------------------------
__global__ __launch_bounds__(256)
void att_kernel(const float* __restrict__ emb, const int* __restrict__ ids,
                const float* __restrict__ w_att, const float* __restrict__ agg,
                float* __restrict__ cur, const int l)
{
    const int wid  = threadIdx.x >> 6;
    const int lane = threadIdx.x & 63;
    const int b    = blockIdx.x * 4 + wid;

    const float* waH  = w_att + l * 2 * ND;
    const float* waT  = waH + ND;
    const float* crow = (l == 0) ? (emb + (size_t)ids[b] * ND) : (cur + (size_t)b * ND);
    const float* ab   = agg + ((size_t)(l * NT) * NB + b) * ND;   // + tt*NB*ND

    const float c1 = crow[lane], c2 = crow[lane + 64];
    const float h1 = waH[lane],  h2 = waH[lane + 64];
    const float t1 = waT[lane],  t2 = waT[lane + 64];
    float g1[3], g2[3];
    #pragma unroll
    for (int tt = 0; tt < 3; ++tt) {
        g1[tt] = ab[(size_t)tt * NB * ND + lane];
        g2[tt] = ab[(size_t)tt * NB * ND + lane + 64];
    }

    float dH = c1 * h1 + c2 * h2;
    float dc = c1 * t1 + c2 * t2;
    float d0 = g1[0] * t1 + g2[0] * t2;
    float d1 = g1[1] * t1 + g2[1] * t2;
    float d2 = g1[2] * t1 + g2[2] * t2;
    #pragma unroll
    for (int off = 32; off > 0; off >>= 1) {
        dH += __shfl_xor(dH, off);
        dc += __shfl_xor(dc, off);
        d0 += __shfl_xor(d0, off);
        d1 += __shfl_xor(d1, off);
        d2 += __shfl_xor(d2, off);
    }

    float s0 = dH + dc, s1 = dH + d0, s2 = dH + d1, s3 = dH + d2;
    float m  = fmaxf(fmaxf(s0, s1), fmaxf(s2, s3));
    float q0 = __expf(s0 - m), q1 = __expf(s1 - m), q2 = __expf(s2 - m), q3 = __expf(s3 - m);
    float inv = __fdividef(1.0f, q0 + q1 + q2 + q3);
    float w0 = q0 * inv, w1 = q1 * inv, w2 = q2 * inv, w3 = q3 * inv;

    float o1 = w0 * c1 + w1 * g1[0] + w2 * g1[1] + w3 * g1[2];
    float o2 = w0 * c2 + w1 * g2[0] + w2 * g2[1] + w3 * g2[2];
    o1 = (o1 > 0.f) ? o1 : 0.01f * o1;
    o2 = (o2 > 0.f) ? o2 : 0.01f * o2;

    float* orow = cur + (size_t)b * ND;
    orow[lane]      = o1;
    orow[lane + 64] = o2;
}

extern "C" void kernel_launch(void* const* d_in, const int* in_sizes, int n_in,
                              void* d_out, int out_size, void* d_ws, size_t ws_size,
                              hipStream_t stream)
{
    const float* emb  = (const float*)d_in[0];
    const float* Wih  = (const float*)d_in[1];
    const float* Whh  = (const float*)d_in[2];
    const float* bih  = (const float*)d_in[3];
    const float* bhh  = (const float*)d_in[4];
    const float* watt = (const float*)d_in[5];
    const int*   ids  = (const int*)d_in[6];
    const int*   nidx = (const int*)d_in[7];

    float* cur = (float*)d_out;            // [B][D] fp32, final output
    float* agg = (float*)d_ws;             // [L][T][B][D] fp32 = 25 MB

    rnn_kernel<<<dim3(NL * NT * (NB / ROWS)), dim3(256), 0, stream>>>(emb, Wih, Whh, bih, bhh, nidx, agg);
    att_kernel<<<dim3(NB / 4), dim3(256), 0, stream>>>(emb, ids, watt, agg, cur, 0);
    att_kernel<<<dim3(NB / 4), dim3(256), 0, stream>>>(emb, ids, watt, agg, cur, 1);
}

// Round 9
// 76.203 us; speedup vs baseline: 2.4617x; 1.1668x over previous
//
#include <hip/hip_runtime.h>
#include <hip/hip_bf16.h>

#define NB   8192   // batch
#define NS   10     // neighbor seq len
#define NT   3      // node types
#define NN   65536  // table size
#define ND   128    // embed dim
#define NL   2      // layers
#define ROWS 32     // batch rows per block

typedef __attribute__((ext_vector_type(8))) short bf16x8;
typedef __attribute__((ext_vector_type(4))) float f32x4;

__device__ __forceinline__ unsigned int pk2(float lo, float hi) {
    unsigned int r;
    asm("v_cvt_pk_bf16_f32 %0, %1, %2" : "=v"(r) : "v"(lo), "v"(hi));
    return r;
}
// tanh(x) = 1 - 2/(exp2(2*log2e*x)+1): mul, exp, add, rcp, fma (2 trans)
__device__ __forceinline__ float tanh_f(float x) {
    float e, r;
    asm("v_exp_f32 %0, %1" : "=v"(e) : "v"(x * 2.88539004f));
    asm("v_rcp_f32 %0, %1" : "=v"(r) : "v"(e + 1.0f));
    return fmaf(-2.0f, r, 1.0f);
}
// Barrier with LDS-only drain: global (vmcnt) loads stay in flight across it.
__device__ __forceinline__ void bar_lgkm() {
    asm volatile("s_waitcnt lgkmcnt(0)\n\ts_barrier" ::: "memory");
}

// ---------------------------------------------------------------------------
// RNN kernel, layer-fused: grid = NT*256 blocks, 512 threads (8 waves).
// Block owns (t, 32 batch rows) and computes BOTH layers: waves 0-3 = layer 0
// (e-slices of 32), waves 4-7 = layer 1. X_s gathered+staged ONCE per step for
// both layers. W2=[Wih;Whh] slice in registers per wave. X and per-layer H
// double-buffered in LDS (XOR-swizzled 16B chunks); ONE lgkm-only barrier per
// step; register gather prefetch stays in flight across it (vmcnt undrained).
// s-loop fully unrolled: buffer parity & ds offsets are compile-time.
// ---------------------------------------------------------------------------
__global__ __launch_bounds__(512)
void rnn_kernel(const float* __restrict__ emb, const float* __restrict__ Wih,
                const float* __restrict__ Whh, const float* __restrict__ bih,
                const float* __restrict__ bhh, const int* __restrict__ nidx,
                float* __restrict__ agg)
{
    // [X p0 | X p1 | H(l0) p0 | H(l0) p1 | H(l1) p0 | H(l1) p1], 8 KB each
    __shared__ __align__(16) char lds[6 * 8192];

    const int bid = blockIdx.x;                 // NT * (NB/ROWS)
    const int t   = bid / (NB / ROWS);
    const int b0  = (bid % (NB / ROWS)) * ROWS;

    const int tid  = threadIdx.x;
    const int wv   = tid >> 6;
    const int lay  = wv >> 2;        // layer 0/1
    const int lane = tid & 63;
    const int l16  = lane & 15;
    const int lg   = lane >> 4;
    const int e0   = (wv & 3) * 32;  // e-slice within layer
    const int rx   = l16 & 7;        // read-swizzle key

    char* xb = lds;
    char* hb = lds + 16384 + lay * 16384;

    // staging geometry: 16 threads per row, 8 floats (one 16B bf16 chunk) each
    const int srow  = tid >> 4;      // 0..31
    const int sq    = tid & 15;      // chunk index
    const int xaddr = srow * 256 + ((sq ^ (srow & 7)) << 4);

    // ---- preload all neighbor indices for this row ----
    const int* ip = nidx + ((size_t)t * NB + b0 + srow) * NS;
    int idxs[NS];
    #pragma unroll
    for (int s = 0; s < NS; ++s) idxs[s] = ip[s];

    // ---- prefetch s=0 gather (lands while W-fragments are built) ----
    float4 P0, P1;
    {
        const float* src = emb + ((size_t)t * NN + idxs[0]) * ND + sq * 8;
        P0 = *(const float4*)(src);
        P1 = *(const float4*)(src + 4);
    }

    const float* Wih_lt = Wih + (size_t)(lay * NT + t) * ND * ND;
    const float* Whh_lt = Whh + (size_t)(lay * NT + t) * ND * ND;
    const float* bih_lt = bih + (size_t)(lay * NT + t) * ND;
    const float* bhh_lt = bhh + (size_t)(lay * NT + t) * ND;

    // ---- A-fragments: rows e = e0 + mt*16 + l16, k-chunk kc (kc<4: Wih) ----
    bf16x8 Af[2][8];
    #pragma unroll
    for (int mt = 0; mt < 2; ++mt) {
        #pragma unroll
        for (int kc = 0; kc < 8; ++kc) {
            const float* Wsrc = (kc < 4) ? Wih_lt : Whh_lt;
            const float* srcp = Wsrc + (size_t)(e0 + mt * 16 + l16) * ND + (kc & 3) * 32 + lg * 8;
            float4 p0 = *(const float4*)(srcp);
            float4 p1 = *(const float4*)(srcp + 4);
            int4 a;
            a.x = (int)pk2(p0.x, p0.y);
            a.y = (int)pk2(p0.z, p0.w);
            a.z = (int)pk2(p1.x, p1.y);
            a.w = (int)pk2(p1.z, p1.w);
            Af[mt][kc] = *(bf16x8*)&a;
        }
    }

    // bias folded into MFMA C-init
    f32x4 biasv[2];
    #pragma unroll
    for (int mt = 0; mt < 2; ++mt)
        #pragma unroll
        for (int i = 0; i < 4; ++i) {
            int e = e0 + mt * 16 + lg * 4 + i;
            biasv[mt][i] = bih_lt[e] + bhh_lt[e];
        }

    // precomputed swizzled LDS addresses (buffer parity via imm offsets)
    int raddr[2][4];   // B-frag reads (X and H share the pattern)
    #pragma unroll
    for (int nt = 0; nt < 2; ++nt)
        #pragma unroll
        for (int c = 0; c < 4; ++c)
            raddr[nt][c] = (nt * 16 + l16) * 256 + (((c * 4 + lg) ^ rx) << 4);
    int hwaddr[2][2];  // packed H writes
    #pragma unroll
    for (int nt = 0; nt < 2; ++nt)
        #pragma unroll
        for (int mt = 0; mt < 2; ++mt) {
            int es = e0 + mt * 16 + lg * 4;
            hwaddr[nt][mt] = (nt * 16 + l16) * 256 + (((es >> 3) ^ rx) << 4) + (es & 7) * 2;
        }

    f32x4 zero4; zero4[0] = 0.f; zero4[1] = 0.f; zero4[2] = 0.f; zero4[3] = 0.f;
    f32x4 Ag[2][2];
    #pragma unroll
    for (int nt = 0; nt < 2; ++nt) { Ag[nt][0] = zero4; Ag[nt][1] = zero4; }

    #pragma unroll
    for (int s = 0; s < NS; ++s) {
        // ---- pack prefetched X_s -> swizzled LDS store (1x ds_write_b128) ----
        {
            int4 pk;
            pk.x = (int)pk2(P0.x, P0.y);
            pk.y = (int)pk2(P0.z, P0.w);
            pk.z = (int)pk2(P1.x, P1.y);
            pk.w = (int)pk2(P1.z, P1.w);
            *(int4*)(xb + xaddr + (s & 1) * 8192) = pk;
        }
        // ---- issue next-step gather; stays in flight across the barrier ----
        if (s + 1 < NS) {
            const float* src = emb + ((size_t)t * NN + idxs[s + 1]) * ND + sq * 8;
            P0 = *(const float4*)(src);
            P1 = *(const float4*)(src + 4);
        }
        bar_lgkm();   // X_s and H_{s-1} visible to all 8 waves; vmcnt in flight

        // ---- acc = bias + W2-rows x Z-rows (K=256: X then H of own layer) ----
        f32x4 acc[2][2];
        #pragma unroll
        for (int nt = 0; nt < 2; ++nt) { acc[nt][0] = biasv[0]; acc[nt][1] = biasv[1]; }

        #pragma unroll
        for (int nt = 0; nt < 2; ++nt)
            #pragma unroll
            for (int c = 0; c < 4; ++c) {
                bf16x8 bf = *(const bf16x8*)(xb + raddr[nt][c] + (s & 1) * 8192);
                acc[nt][0] = __builtin_amdgcn_mfma_f32_16x16x32_bf16(Af[0][c], bf, acc[nt][0], 0, 0, 0);
                acc[nt][1] = __builtin_amdgcn_mfma_f32_16x16x32_bf16(Af[1][c], bf, acc[nt][1], 0, 0, 0);
            }
        if (s > 0) {
            #pragma unroll
            for (int nt = 0; nt < 2; ++nt)
                #pragma unroll
                for (int c = 0; c < 4; ++c) {
                    bf16x8 bf = *(const bf16x8*)(hb + raddr[nt][c] + ((s + 1) & 1) * 8192);
                    acc[nt][0] = __builtin_amdgcn_mfma_f32_16x16x32_bf16(Af[0][c + 4], bf, acc[nt][0], 0, 0, 0);
                    acc[nt][1] = __builtin_amdgcn_mfma_f32_16x16x32_bf16(Af[1][c + 4], bf, acc[nt][1], 0, 0, 0);
                }
        }

        // ---- tanh + agg accumulate + packed H writeback (other H buffer) ----
        #pragma unroll
        for (int nt = 0; nt < 2; ++nt)
            #pragma unroll
            for (int mt = 0; mt < 2; ++mt) {
                f32x4 h;
                #pragma unroll
                for (int i = 0; i < 4; ++i)
                    h[i] = tanh_f(acc[nt][mt][i]);
                Ag[nt][mt] += h;
                int2 pk;
                pk.x = (int)pk2(h[0], h[1]);
                pk.y = (int)pk2(h[2], h[3]);
                *(int2*)(hb + hwaddr[nt][mt] + (s & 1) * 8192) = pk;
            }
    }

    // agg[l][t][b][e]: lane writes float4 of 4 consecutive e at its row b
    float* aggp = agg + ((size_t)(lay * NT + t) * NB + b0) * ND;
    #pragma unroll
    for (int nt = 0; nt < 2; ++nt) {
        int b = nt * 16 + l16;
        #pragma unroll
        for (int mt = 0; mt < 2; ++mt) {
            f32x4 v = Ag[nt][mt] * 0.1f;
            *(f32x4*)(aggp + (size_t)b * ND + e0 + mt * 16 + lg * 4) = v;
        }
    }
}

// ---------------------------------------------------------------------------
// Attention: one wave per batch row (lane covers d and d+64). 5 dots via
// shuffle reduce, softmax(4), weighted sum, leaky_relu. 2048 blocks x 256.
// ---------------------------------------------------------------------------
__global__ __launch_bounds__(256)
void att_kernel(const float* __restrict__ emb, const int* __restrict__ ids,
                const float* __restrict__ w_att, const float* __restrict__ agg,
                float* __restrict__ cur, const int l)
{
    const int wid  = threadIdx.x >> 6;
    const int lane = threadIdx.x & 63;
    const int b    = blockIdx.x * 4 + wid;

    const float* waH  = w_att + l * 2 * ND;
    const float* waT  = waH + ND;
    const float* crow = (l == 0) ? (emb + (size_t)ids[b] * ND) : (cur + (size_t)b * ND);
    const float* ab   = agg + ((size_t)(l * NT) * NB + b) * ND;   // + tt*NB*ND

    const float c1 = crow[lane], c2 = crow[lane + 64];
    const float h1 = waH[lane],  h2 = waH[lane + 64];
    const float t1 = waT[lane],  t2 = waT[lane + 64];
    float g1[3], g2[3];
    #pragma unroll
    for (int tt = 0; tt < 3; ++tt) {
        g1[tt] = ab[(size_t)tt * NB * ND + lane];
        g2[tt] = ab[(size_t)tt * NB * ND + lane + 64];
    }

    float dH = c1 * h1 + c2 * h2;
    float dc = c1 * t1 + c2 * t2;
    float d0 = g1[0] * t1 + g2[0] * t2;
    float d1 = g1[1] * t1 + g2[1] * t2;
    float d2 = g1[2] * t1 + g2[2] * t2;
    #pragma unroll
    for (int off = 32; off > 0; off >>= 1) {
        dH += __shfl_xor(dH, off);
        dc += __shfl_xor(dc, off);
        d0 += __shfl_xor(d0, off);
        d1 += __shfl_xor(d1, off);
        d2 += __shfl_xor(d2, off);
    }

    float s0 = dH + dc, s1 = dH + d0, s2 = dH + d1, s3 = dH + d2;
    float m  = fmaxf(fmaxf(s0, s1), fmaxf(s2, s3));
    float q0 = __expf(s0 - m), q1 = __expf(s1 - m), q2 = __expf(s2 - m), q3 = __expf(s3 - m);
    float inv = __fdividef(1.0f, q0 + q1 + q2 + q3);
    float w0 = q0 * inv, w1 = q1 * inv, w2 = q2 * inv, w3 = q3 * inv;

    float o1 = w0 * c1 + w1 * g1[0] + w2 * g1[1] + w3 * g1[2];
    float o2 = w0 * c2 + w1 * g2[0] + w2 * g2[1] + w3 * g2[2];
    o1 = (o1 > 0.f) ? o1 : 0.01f * o1;
    o2 = (o2 > 0.f) ? o2 : 0.01f * o2;

    float* orow = cur + (size_t)b * ND;
    orow[lane]      = o1;
    orow[lane + 64] = o2;
}

extern "C" void kernel_launch(void* const* d_in, const int* in_sizes, int n_in,
                              void* d_out, int out_size, void* d_ws, size_t ws_size,
                              hipStream_t stream)
{
    const float* emb  = (const float*)d_in[0];
    const float* Wih  = (const float*)d_in[1];
    const float* Whh  = (const float*)d_in[2];
    const float* bih  = (const float*)d_in[3];
    const float* bhh  = (const float*)d_in[4];
    const float* watt = (const float*)d_in[5];
    const int*   ids  = (const int*)d_in[6];
    const int*   nidx = (const int*)d_in[7];

    float* cur = (float*)d_out;            // [B][D] fp32, final output
    float* agg = (float*)d_ws;             // [L][T][B][D] fp32 = 25 MB

    rnn_kernel<<<dim3(NT * (NB / ROWS)), dim3(512), 0, stream>>>(emb, Wih, Whh, bih, bhh, nidx, agg);
    att_kernel<<<dim3(NB / 4), dim3(256), 0, stream>>>(emb, ids, watt, agg, cur, 0);
    att_kernel<<<dim3(NB / 4), dim3(256), 0, stream>>>(emb, ids, watt, agg, cur, 1);
}